// Round 9
// baseline (189.232 us; speedup 1.0000x reference)
//
#include <hip/hip_runtime.h>
#include <math.h>
#include <limits.h>

// Match numpy op-for-op: no fma contraction anywhere.
#pragma clang fp contract(off)

#define TPB 256
#define ATPB 64
#define KTOP 10
#define ISPLIT 64
#define GCAP 4096
#define MAXG 512
#define MAXMULTI 4096

typedef unsigned int u32;
typedef unsigned char u8;

// pairwise IoU, identical op order to the numpy reference
__device__ __forceinline__ float f_iou(float ax0, float ay0, float ax1, float ay1,
                                       float bx0, float by0, float bx1, float by1) {
  float tlx = fmaxf(ax0, bx0);
  float tly = fmaxf(ay0, by0);
  float brx = fminf(ax1, bx1);
  float bry = fminf(ay1, by1);
  float w = fmaxf(brx - tlx, 0.0f);
  float h = fmaxf(bry - tly, 0.0f);
  float inter = w * h;
  float aa = fmaxf(ax1 - ax0, 0.0f) * fmaxf(ay1 - ay0, 0.0f);
  float ab = fmaxf(bx1 - bx0, 0.0f) * fmaxf(by1 - by0, 0.0f);
  float uni = aa + ab - inter;
  return inter / fmaxf(uni, 1e-7f);
}

// dv = -(L - L1), exact expression tree of the reference cls numerator
__device__ __forceinline__ float f_dv(float p) {
  float L  = fmaxf(logf(p), -100.0f);
  float L1 = fmaxf(log1pf(-p), -100.0f);
  return -(L - L1);
}

// full cost(n,g); identical op order to reference (cls = dv - sumL1).
__device__ __forceinline__ float f_cost(float iou_masked, float dv, float sumL1v,
                                        float px, float py, float sx, float sy,
                                        float bx0, float by0, float bx1, float by1,
                                        int vld) {
  if (!vld) return 100000000.0f;  // BIG
  float cls = dv - sumL1v;
  float l_ = px - bx0, t_ = py - by0, r_ = bx1 - px, b_ = by1 - py;
  bool ing = fminf(fminf(l_, t_), fminf(r_, b_)) > 0.0f;
  float gcx = (bx0 + bx1) * 0.5f;
  float gcy = (by0 + by1) * 0.5f;
  float cl = px - (gcx - 2.5f * sx);
  float ct = py - (gcy - 2.5f * sy);
  float cr = (gcx + 2.5f * sx) - px;
  float cb = (gcy + 2.5f * sy) - py;
  bool inc = fminf(fminf(cl, ct), fminf(cr, cb)) > 0.0f;
  float icost = -logf(iou_masked + 1e-7f);
  return (cls * 1.0f + icost * 3.0f) + ((ing && inc) ? 0.0f : 100000.0f);
}

// Fallback: distinct sentinel so a too-small workspace is diagnosable.
__global__ __launch_bounds__(TPB) void k_fallback(float* out, int Nout) {
  int n = blockIdx.x * blockDim.x + threadIdx.x;
  if (n >= Nout) return;
  out[n] = 0.0f;
  out[Nout + n] = -1.0f;
  out[2 * Nout + n] = -70000.0f;
}

// Kernel 1: 8 threads per anchor. valid via shfl-OR; sumL1 via 8 lane accs +
// shfl-down tree (== numpy pairwise order); writes decv (invalid -> degenerate
// box, iou==0 exactly); appends gated (in_box&&in_center) pairs per g.
__global__ __launch_bounds__(TPB) void k_pre(
    const float* pred, const float* priors, const float* dec, const float* gtb,
    float* sumL1, u8* validArr, u32* packed, float4* decv,
    int* gateCnt, int* gateList, int* flags, int* mcnt,
    int N, int G, int C)
{
  __shared__ float sg[MAXG * 4];
  for (int i = threadIdx.x; i < G * 4; i += blockDim.x) sg[i] = gtb[i];
  __syncthreads();
  int t = blockIdx.x * blockDim.x + threadIdx.x;
  if (t == 0) *mcnt = 0;
  int n = t >> 3;
  int j = t & 7;
  if (n >= N) return;
  const float4 pv = reinterpret_cast<const float4*>(priors)[n];
  float px = pv.x, py = pv.y, sx = pv.z, sy = pv.w;

  int valid = 0;
  for (int g = j; g < G; g += 8) {
    float x0 = sg[g * 4 + 0], y0 = sg[g * 4 + 1], x1 = sg[g * 4 + 2], y1 = sg[g * 4 + 3];
    float l_ = px - x0, t_ = py - y0, r_ = x1 - px, b_ = y1 - py;
    bool ing = fminf(fminf(l_, t_), fminf(r_, b_)) > 0.0f;
    float gcx = (x0 + x1) * 0.5f, gcy = (y0 + y1) * 0.5f;
    float cl = px - (gcx - 2.5f * sx), ct = py - (gcy - 2.5f * sy);
    float cr = (gcx + 2.5f * sx) - px, cb = (gcy + 2.5f * sy) - py;
    bool inc = fminf(fminf(cl, ct), fminf(cr, cb)) > 0.0f;
    valid |= (ing || inc) ? 1 : 0;
    if (ing && inc) {
      int slot = atomicAdd(&gateCnt[g], 1);
      if (slot < GCAP) gateList[g * GCAP + slot] = n;
      else flags[g] = 1;  // overflow -> exact full-scan fallback for this g
    }
  }
  valid |= __shfl_xor(valid, 1, 8);
  valid |= __shfl_xor(valid, 2, 8);
  valid |= __shfl_xor(valid, 4, 8);

  // lane j: classes i ≡ j (mod 8) ascending == numpy 8-accumulator order;
  // shfl-down tree == ((r0+r1)+(r2+r3))+((r4+r5)+(r6+r7)).
  const float* pr = pred + (size_t)n * C;
  int lim = C - (C % 8);
  float r = 0.0f;
  for (int i = j; i < lim; i += 8) r += fmaxf(log1pf(-pr[i]), -100.0f);
  r += __shfl_down(r, 1, 8);
  r += __shfl_down(r, 2, 8);
  r += __shfl_down(r, 4, 8);
  if (j == 0) {
    for (int i = lim; i < C; ++i) r += fmaxf(log1pf(-pr[i]), -100.0f);
    sumL1[n] = r;
    validArr[n] = (u8)valid;
    packed[n] = 0;  // ws is re-poisoned every launch — must re-zero
    const float4 dvb = reinterpret_cast<const float4*>(dec)[n];
    float4 o;
    if (valid) o = dvb;
    else { o.x = 0.0f; o.y = 0.0f; o.z = 0.0f; o.w = 0.0f; }  // iou == 0 exactly
    decv[n] = o;
  }
}

// Kernel 2: ONE WAVE per (g, split), ISPLIT=64 -> 8192 waves (full occupancy).
// Only iv[10] live; zero-init (iou>=0; zero-pad sum-invariant) so the ~95% of
// zero-iou pairs skip the insert. Single decv load per pair.
__global__ __launch_bounds__(ATPB) void k_iou_part(
    const float4* decv, const float* gtb, float* iouV, int N, int G)
{
  int bid = blockIdx.x;
  int g = bid / ISPLIT;
  int s = bid % ISPLIT;
  int chunk = (N + ISPLIT - 1) / ISPLIT;
  int start = s * chunk;
  int end = start + chunk; if (end > N) end = N;
  int tid = threadIdx.x;
  float bx0 = gtb[g * 4 + 0];
  float by0 = gtb[g * 4 + 1];
  float bx1 = gtb[g * 4 + 2];
  float by1 = gtb[g * 4 + 3];

  float iv[KTOP];
#pragma unroll
  for (int j = 0; j < KTOP; ++j) iv[j] = 0.0f;

  for (int n = start + tid; n < end; n += ATPB) {
    float4 dvb = decv[n];
    float iou = f_iou(dvb.x, dvb.y, dvb.z, dvb.w, bx0, by0, bx1, by1);
    if (iou > iv[KTOP - 1]) {
      float cu = iou;
#pragma unroll
      for (int j = 0; j < KTOP; ++j) {
        if (cu > iv[j]) { float tv = iv[j]; iv[j] = cu; cu = tv; }
      }
    }
  }

  // wave tournament: 10 rounds max + owner pop (values only)
#pragma unroll
  for (int r = 0; r < KTOP; ++r) {
    float v = iv[0]; int owner = tid;
#pragma unroll
    for (int off = 32; off > 0; off >>= 1) {
      float v2 = __shfl_down(v, off);
      int o2 = __shfl_down(owner, off);
      if (v2 > v || (v2 == v && o2 < owner)) { v = v2; owner = o2; }
    }
    float wv = __shfl(v, 0);
    int wo = __shfl(owner, 0);
    if (tid == 0) iouV[bid * KTOP + r] = wv;
    if (tid == wo) {
#pragma unroll
      for (int j = 0; j < KTOP - 1; ++j) iv[j] = iv[j + 1];
      iv[KTOP - 1] = 0.0f;
    }
  }
}

// Kernel 3: one 64-thread block per g. (a) top-10 of ISPLIT*10 iou values ->
// dynamic_k; (b) cost eval over that g's gated candidates only (gated cost is
// strictly below any ungated/invalid cost, so when gateCnt>=10 the global
// top-10 is exactly the gated top-10). Lexicographic (cost,n) everywhere ->
// selection independent of append order. Flagged g's defer to k_fb_scan.
__global__ __launch_bounds__(ATPB) void k_merge(
    const float* iouV, const int* gateCnt, const int* gateList, const int* flags,
    const float* pred, const float* priors, const float* dec, const float* sumL1,
    const int* gtl, const float* gtb,
    u32* packed, int* dkArr, int G, int N, int C)
{
  int g = blockIdx.x;
  int tid = threadIdx.x;
  int base = g * ISPLIT * KTOP;
  const int TOT = ISPLIT * KTOP;            // 640
  const int PER = TOT / ATPB;               // 10

  // --- iou: top-10 of TOT values (zero-padded; sum invariant) ---
  float il[PER];
#pragma unroll
  for (int k = 0; k < PER; ++k) il[k] = 0.0f;
#pragma unroll
  for (int k = 0; k < PER; ++k) {
    float v = iouV[base + tid + k * ATPB];
    if (v > il[PER - 1]) {
#pragma unroll
      for (int j = 0; j < PER; ++j) {
        if (v > il[j]) { float tv = il[j]; il[j] = v; v = tv; }
      }
    }
  }
  float rv[KTOP];
#pragma unroll
  for (int r = 0; r < KTOP; ++r) {
    float v = il[0]; int owner = tid;
#pragma unroll
    for (int off = 32; off > 0; off >>= 1) {
      float v2 = __shfl_down(v, off);
      int o2 = __shfl_down(owner, off);
      if (v2 > v || (v2 == v && o2 < owner)) { v = v2; owner = o2; }
    }
    float wv = __shfl(v, 0);
    int wo = __shfl(owner, 0);
    rv[r] = wv;
    if (tid == wo) {
#pragma unroll
      for (int j = 0; j < PER - 1; ++j) il[j] = il[j + 1];
      il[PER - 1] = 0.0f;
    }
  }
  // numpy pairwise order for a 10-element sum (all lanes identical)
  float s8 = ((rv[0] + rv[1]) + (rv[2] + rv[3])) + ((rv[4] + rv[5]) + (rv[6] + rv[7]));
  s8 += rv[8];
  s8 += rv[9];
  int dk = (int)s8;  // trunc toward zero == astype(int32)
  if (dk < 1) dk = 1;
  if (dk > KTOP) dk = KTOP;
  if (tid == 0) dkArr[g] = dk;

  int cnt = gateCnt[g];
  if (flags[g] || cnt < KTOP) return;  // exact fallback handles this g

  // --- cost over gated candidates (all valid, penalty term == +0.0f) ---
  float bx0 = gtb[g * 4 + 0];
  float by0 = gtb[g * 4 + 1];
  float bx1 = gtb[g * 4 + 2];
  float by1 = gtb[g * 4 + 3];
  int lab = gtl[g];
  if (lab < 0) lab = 0;
  if (lab >= C) lab = C - 1;

  float cv[KTOP]; int ci[KTOP];
#pragma unroll
  for (int j = 0; j < KTOP; ++j) { cv[j] = 1e30f; ci[j] = INT_MAX; }
  const float4* dec4 = reinterpret_cast<const float4*>(dec);
  const float4* pri4 = reinterpret_cast<const float4*>(priors);
  const int* gl = gateList + (size_t)g * GCAP;

  for (int i = tid; i < cnt; i += ATPB) {
    int n = gl[i];
    float4 dvb = dec4[n];
    float iou = f_iou(dvb.x, dvb.y, dvb.z, dvb.w, bx0, by0, bx1, by1);
    float dv = f_dv(pred[(size_t)n * C + lab]);
    float cls = dv - sumL1[n];
    float icost = -logf(iou + 1e-7f);
    float c = (cls * 1.0f + icost * 3.0f) + 0.0f;  // gate true -> +0.0 exactly
    (void)pri4;
    // lexicographic (c, n) insert — canonical regardless of arrival order
    bool ins = (c < cv[KTOP - 1]) || (c == cv[KTOP - 1] && n < ci[KTOP - 1]);
    if (ins) {
      float cu = c; int cui = n;
#pragma unroll
      for (int j = 0; j < KTOP; ++j) {
        bool lt = (cu < cv[j]) || (cu == cv[j] && cui < ci[j]);
        if (lt) { float tv = cv[j]; int ti = ci[j]; cv[j] = cu; ci[j] = cui; cu = tv; cui = ti; }
      }
    }
  }

  // wave tournament: dk rounds of lexicographic min, scatter
  for (int r = 0; r < KTOP; ++r) {
    float v = cv[0]; int idx = ci[0];
#pragma unroll
    for (int off = 32; off > 0; off >>= 1) {
      float v2 = __shfl_down(v, off);
      int i2 = __shfl_down(idx, off);
      if (v2 < v || (v2 == v && i2 < idx)) { v = v2; idx = i2; }
    }
    int wi = __shfl(idx, 0);
    if (r < dk && tid == 0 && wi >= 0 && wi < N) {
      // count in high 16 bits; sum of g in low 16 (exact g when count==1)
      atomicAdd(&packed[wi], (1u << 16) | (u32)g);
    }
    if (ci[0] == wi) {  // candidate n unique per g -> exactly one lane pops
#pragma unroll
      for (int j = 0; j < KTOP - 1; ++j) { cv[j] = cv[j + 1]; ci[j] = ci[j + 1]; }
      cv[KTOP - 1] = 1e30f; ci[KTOP - 1] = INT_MAX;
    }
    if (r + 1 >= dk) break;
  }
}

// Exact full-scan fallback for flagged g (gateCnt<10 or overflow) — rare/never.
__global__ __launch_bounds__(TPB) void k_fb_scan(
    const float* pred, const float* priors, const float* dec, const float* gtb,
    const int* gtl, const float* sumL1, const u8* validArr,
    const int* gateCnt, const int* flags, const int* dkArr,
    u32* packed, int N, int G, int C)
{
  int g = blockIdx.x;
  if (!(flags[g] || gateCnt[g] < KTOP)) return;
  int tid = threadIdx.x;
  float bx0 = gtb[g * 4 + 0];
  float by0 = gtb[g * 4 + 1];
  float bx1 = gtb[g * 4 + 2];
  float by1 = gtb[g * 4 + 3];
  int lab = gtl[g];
  if (lab < 0) lab = 0;
  if (lab >= C) lab = C - 1;

  float cv[KTOP]; int ci[KTOP];
  for (int j = 0; j < KTOP; ++j) { cv[j] = 1e30f; ci[j] = INT_MAX; }
  const float4* dec4 = reinterpret_cast<const float4*>(dec);
  const float4* pri4 = reinterpret_cast<const float4*>(priors);

  for (int n = tid; n < N; n += TPB) {
    float4 dvb = dec4[n];
    int vld = validArr[n];
    float iou = f_iou(dvb.x, dvb.y, dvb.z, dvb.w, bx0, by0, bx1, by1);
    if (!vld) iou = 0.0f;
    float dv = f_dv(pred[(size_t)n * C + lab]);
    float4 pv = pri4[n];
    float c = f_cost(iou, dv, sumL1[n], pv.x, pv.y, pv.z, pv.w, bx0, by0, bx1, by1, vld);
    bool ins = (c < cv[KTOP - 1]) || (c == cv[KTOP - 1] && n < ci[KTOP - 1]);
    if (ins) {
      float cu = c; int cui = n;
      for (int j = 0; j < KTOP; ++j) {
        bool lt = (cu < cv[j]) || (cu == cv[j] && cui < ci[j]);
        if (lt) { float tv = cv[j]; int ti = ci[j]; cv[j] = cu; ci[j] = cui; cu = tv; cui = ti; }
      }
    }
  }

  __shared__ float sv[TPB];
  __shared__ int   si[TPB];
  int dk = dkArr[g];
  for (int r = 0; r < KTOP; ++r) {
    sv[tid] = cv[0]; si[tid] = ci[0];
    __syncthreads();
    for (int st = TPB / 2; st > 0; st >>= 1) {
      if (tid < st) {
        float v2 = sv[tid + st]; int i2 = si[tid + st];
        float v1 = sv[tid];      int i1 = si[tid];
        if (v2 < v1 || (v2 == v1 && i2 < i1)) { sv[tid] = v2; si[tid] = i2; }
      }
      __syncthreads();
    }
    int wi = si[0];
    if (r < dk && tid == 0 && wi >= 0 && wi < N)
      atomicAdd(&packed[wi], (1u << 16) | (u32)g);
    __syncthreads();
    if (ci[0] == wi) {
      for (int j = 0; j < KTOP - 1; ++j) { cv[j] = cv[j + 1]; ci[j] = ci[j + 1]; }
      cv[KTOP - 1] = 1e30f; ci[KTOP - 1] = INT_MAX;
    }
  }
}

// Kernel 4 stage A: resolve cnt==0/1 inline, queue cnt>1 into worklist.
__global__ __launch_bounds__(TPB) void k_final(
    const float* dec, const float* gtb, const u8* validArr, const u32* packed,
    int* mlist, int* mcnt,
    float* out, int N, int G, int Nout)
{
  __shared__ float sg[MAXG * 4];
  for (int i = threadIdx.x; i < G * 4; i += blockDim.x) sg[i] = gtb[i];
  __syncthreads();
  int n = blockIdx.x * blockDim.x + threadIdx.x;
  if (n >= N || n >= Nout) return;
  u32 pk = packed[n];
  int cnt = (int)(pk >> 16);
  float o0 = 0.0f, o1 = -1.0f, o2 = -100000.0f;
  if (cnt > 1) {
    int idx = atomicAdd(mcnt, 1);
    if (idx < MAXMULTI) mlist[idx] = n;
    // outputs for this n written by k_multi (later kernel, no race)
  }
  if (cnt == 1) {
    int g = (int)(pk & 0xFFFFu);
    if (g < 0) g = 0;
    if (g >= G) g = G - 1;
    const float4 dv = reinterpret_cast<const float4*>(dec)[n];
    float x0 = sg[g * 4 + 0], y0 = sg[g * 4 + 1], x1 = sg[g * 4 + 2], y1 = sg[g * 4 + 3];
    float iou = f_iou(dv.x, dv.y, dv.z, dv.w, x0, y0, x1, y1);
    if (!validArr[n]) iou = 0.0f;
    o0 = (float)g; o1 = 1.0f; o2 = iou;
  }
  out[n]            = o0;
  out[Nout + n]     = o1;
  out[2 * Nout + n] = o2;
}

// Kernel 4 stage B: one 128-thread block per multi anchor (grid-stride).
// Lane gg computes cost(n,gg); LDS argmin tree, first-min tie-break == np.argmin.
#define MTPB 128
__global__ __launch_bounds__(MTPB) void k_multi(
    const float* pred, const float* priors, const float* dec,
    const float* gtb, const int* gtl, const float* sumL1, const u8* validArr,
    const int* mlist, const int* mcnt,
    float* out, int N, int G, int C, int Nout)
{
  __shared__ float rv[MTPB];
  __shared__ int   rg[MTPB];
  int tid = threadIdx.x;
  int total = *mcnt;
  if (total > MAXMULTI) total = MAXMULTI;
  for (int w = blockIdx.x; w < total; w += gridDim.x) {
    int n = mlist[w];
    const float4 dvb = reinterpret_cast<const float4*>(dec)[n];
    const float4 pv  = reinterpret_cast<const float4*>(priors)[n];
    float s1 = sumL1[n];
    int vld = validArr[n];
    float best = 1e30f; int bg = INT_MAX;
    for (int gg = tid; gg < G; gg += MTPB) {
      float x0 = gtb[gg * 4 + 0], y0 = gtb[gg * 4 + 1];
      float x1 = gtb[gg * 4 + 2], y1 = gtb[gg * 4 + 3];
      float iou = f_iou(dvb.x, dvb.y, dvb.z, dvb.w, x0, y0, x1, y1);
      if (!vld) iou = 0.0f;
      int lb = gtl[gg];
      if (lb < 0) lb = 0;
      if (lb >= C) lb = C - 1;
      float dv = f_dv(pred[(size_t)n * C + lb]);
      float c = f_cost(iou, dv, s1, pv.x, pv.y, pv.z, pv.w, x0, y0, x1, y1, vld);
      if (c < best || (c == best && gg < bg)) { best = c; bg = gg; }
    }
    rv[tid] = best; rg[tid] = bg;
    __syncthreads();
    for (int st = MTPB / 2; st > 0; st >>= 1) {
      if (tid < st) {
        float v2 = rv[tid + st]; int g2 = rg[tid + st];
        float v1 = rv[tid];      int g1 = rg[tid];
        if (v2 < v1 || (v2 == v1 && g2 < g1)) { rv[tid] = v2; rg[tid] = g2; }
      }
      __syncthreads();
    }
    if (tid == 0) {
      int g = rg[0];
      if (g < 0 || g >= G) g = 0;
      float x0 = gtb[g * 4 + 0], y0 = gtb[g * 4 + 1];
      float x1 = gtb[g * 4 + 2], y1 = gtb[g * 4 + 3];
      float iou = f_iou(dvb.x, dvb.y, dvb.z, dvb.w, x0, y0, x1, y1);
      if (!vld) iou = 0.0f;
      out[n]            = (float)g;
      out[Nout + n]     = 1.0f;
      out[2 * Nout + n] = iou;
    }
    __syncthreads();  // protect rv/rg before next worklist item
  }
}

extern "C" void kernel_launch(void* const* d_in, const int* in_sizes, int n_in,
                              void* d_out, int out_size, void* d_ws, size_t ws_size,
                              hipStream_t stream) {
  const float* pred   = (const float*)d_in[0];  // (N,C) f32
  const float* priors = (const float*)d_in[1];  // (N,4) f32
  const float* dec    = (const float*)d_in[2];  // (N,4) f32
  const float* gtb    = (const float*)d_in[3];  // (G,4) f32
  const int*   gtl    = (const int*)d_in[4];    // (G,)  int32
  int N = in_sizes[2] / 4;
  int G = in_sizes[3] / 4;
  if (G > MAXG) G = MAXG;
  int C = in_sizes[0] / N;
  int Nout = out_size / 3;
  float* out = (float*)d_out;

  // ws layout (16B-aligned blocks):
  // packed u32[N] | sumL1 f32[N] | decv float4[N] | valid u8[N] |
  // mlist i32[MAXMULTI] | mcnt | gateCnt i32[G] flags i32[G] dk i32[G] |
  // gateList i32[G*GCAP] | iouV f32[G*ISPLIT*KTOP]
  size_t offPacked = 0;
  size_t offSum    = offPacked + (size_t)N * 4;
  size_t offDecv   = (offSum + (size_t)N * 4 + 15) & ~(size_t)15;
  size_t offValid  = offDecv + (size_t)N * 16;
  size_t offMlist  = (offValid + (size_t)N + 15) & ~(size_t)15;
  size_t offMcnt   = offMlist + (size_t)MAXMULTI * 4;
  size_t offGate   = (offMcnt + 4 + 15) & ~(size_t)15;
  size_t offGlist  = offGate + (size_t)G * 12;
  size_t offIouV   = offGlist + (size_t)G * GCAP * 4;
  size_t need      = offIouV + (size_t)G * ISPLIT * KTOP * 4;

  dim3 b(TPB);
  int nblk = (N + TPB - 1) / TPB;
  int oblk = (Nout + TPB - 1) / TPB;
  if (ws_size < need || d_ws == nullptr) {
    k_fallback<<<oblk, b, 0, stream>>>(out, Nout);  // sentinel: -70000 at out2
    return;
  }
  char* wsb = (char*)d_ws;
  u32* packed   = (u32*)(wsb + offPacked);
  float* sumL1  = (float*)(wsb + offSum);
  float4* decv  = (float4*)(wsb + offDecv);
  u8* validArr  = (u8*)(wsb + offValid);
  int* mlist    = (int*)(wsb + offMlist);
  int* mcnt     = (int*)(wsb + offMcnt);
  int* gateCnt  = (int*)(wsb + offGate);
  int* flags    = gateCnt + G;
  int* dkArr    = gateCnt + 2 * G;
  int* gateList = (int*)(wsb + offGlist);
  float* iouV   = (float*)(wsb + offIouV);

  // zero gateCnt+flags before k_pre's atomic appends (stream-ordered)
  hipMemsetAsync(gateCnt, 0, (size_t)G * 8, stream);

  int preblk = ((N * 8) + TPB - 1) / TPB;
  k_pre<<<preblk, b, 0, stream>>>(pred, priors, dec, gtb, sumL1, validArr, packed,
                                  decv, gateCnt, gateList, flags, mcnt, N, G, C);
  k_iou_part<<<G * ISPLIT, dim3(ATPB), 0, stream>>>(decv, gtb, iouV, N, G);
  k_merge<<<G, dim3(ATPB), 0, stream>>>(iouV, gateCnt, gateList, flags,
                                        pred, priors, dec, sumL1, gtl, gtb,
                                        packed, dkArr, G, N, C);
  k_fb_scan<<<G, b, 0, stream>>>(pred, priors, dec, gtb, gtl, sumL1, validArr,
                                 gateCnt, flags, dkArr, packed, N, G, C);
  k_final<<<nblk, b, 0, stream>>>(dec, gtb, validArr, packed, mlist, mcnt, out, N, G, Nout);
  k_multi<<<256, dim3(MTPB), 0, stream>>>(pred, priors, dec, gtb, gtl, sumL1, validArr,
                                          mlist, mcnt, out, N, G, C, Nout);
}

// Round 10
// 173.671 us; speedup vs baseline: 1.0896x; 1.0896x over previous
//
#include <hip/hip_runtime.h>
#include <math.h>
#include <limits.h>

// Match numpy op-for-op: no fma contraction anywhere.
#pragma clang fp contract(off)

#define TPB 256
#define ATPB 64
#define KTOP 10
#define ISPLIT 64
#define GSPLIT 16
#define GCAP 4096
#define MAXG 512
#define MAXMULTI 4096

typedef unsigned int u32;
typedef unsigned long long u64;
typedef unsigned char u8;

// pairwise IoU, identical op order to the numpy reference
__device__ __forceinline__ float f_iou(float ax0, float ay0, float ax1, float ay1,
                                       float bx0, float by0, float bx1, float by1) {
  float tlx = fmaxf(ax0, bx0);
  float tly = fmaxf(ay0, by0);
  float brx = fminf(ax1, bx1);
  float bry = fminf(ay1, by1);
  float w = fmaxf(brx - tlx, 0.0f);
  float h = fmaxf(bry - tly, 0.0f);
  float inter = w * h;
  float aa = fmaxf(ax1 - ax0, 0.0f) * fmaxf(ay1 - ay0, 0.0f);
  float ab = fmaxf(bx1 - bx0, 0.0f) * fmaxf(by1 - by0, 0.0f);
  float uni = aa + ab - inter;
  return inter / fmaxf(uni, 1e-7f);
}

// dv = -(L - L1), exact expression tree of the reference cls numerator
__device__ __forceinline__ float f_dv(float p) {
  float L  = fmaxf(logf(p), -100.0f);
  float L1 = fmaxf(log1pf(-p), -100.0f);
  return -(L - L1);
}

// full cost(n,g); identical op order to reference (cls = dv - sumL1).
__device__ __forceinline__ float f_cost(float iou_masked, float dv, float sumL1v,
                                        float px, float py, float sx, float sy,
                                        float bx0, float by0, float bx1, float by1,
                                        int vld) {
  if (!vld) return 100000000.0f;  // BIG
  float cls = dv - sumL1v;
  float l_ = px - bx0, t_ = py - by0, r_ = bx1 - px, b_ = by1 - py;
  bool ing = fminf(fminf(l_, t_), fminf(r_, b_)) > 0.0f;
  float gcx = (bx0 + bx1) * 0.5f;
  float gcy = (by0 + by1) * 0.5f;
  float cl = px - (gcx - 2.5f * sx);
  float ct = py - (gcy - 2.5f * sy);
  float cr = (gcx + 2.5f * sx) - px;
  float cb = (gcy + 2.5f * sy) - py;
  bool inc = fminf(fminf(cl, ct), fminf(cr, cb)) > 0.0f;
  float icost = -logf(iou_masked + 1e-7f);
  return (cls * 1.0f + icost * 3.0f) + ((ing && inc) ? 0.0f : 100000.0f);
}

// Fallback: distinct sentinel so a too-small workspace is diagnosable.
__global__ __launch_bounds__(TPB) void k_fallback(float* out, int Nout) {
  int n = blockIdx.x * blockDim.x + threadIdx.x;
  if (n >= Nout) return;
  out[n] = 0.0f;
  out[Nout + n] = -1.0f;
  out[2 * Nout + n] = -70000.0f;
}

// Kernel 1: sumL1 only. 8 lanes per anchor; lane j owns classes i ≡ j (mod 8)
// ascending == numpy 8-accumulator pairwise order; shfl-down tree == its
// combine. Pure streaming — no LDS, no atomics, no branches.
__global__ __launch_bounds__(TPB) void k_sum(
    const float* pred, float* sumL1, u32* packed, int N, int C)
{
  int t = blockIdx.x * blockDim.x + threadIdx.x;
  int n = t >> 3;
  int j = t & 7;
  if (n >= N) return;
  const float* pr = pred + (size_t)n * C;
  int lim = C - (C % 8);
  float r = 0.0f;
  for (int i = j; i < lim; i += 8) r += fmaxf(log1pf(-pr[i]), -100.0f);
  r += __shfl_down(r, 1, 8);
  r += __shfl_down(r, 2, 8);
  r += __shfl_down(r, 4, 8);
  if (j == 0) {
    for (int i = lim; i < C; ++i) r += fmaxf(log1pf(-pr[i]), -100.0f);
    sumL1[n] = r;
    packed[n] = 0;  // ws re-poisoned every launch — must re-zero
  }
}

// Kernel 2: one WAVE per (g, split). Gate test per pair; valid[n] via benign
// same-value byte store; gate append via wave-aggregated atomic (one
// atomicAdd per wave-iteration, ballot+popc prefix scatter).
__global__ __launch_bounds__(ATPB) void k_gate(
    const float* priors, const float* gtb,
    u8* validArr, int* gateCnt, int* gateList, int* flags,
    int N, int G)
{
  int bid = blockIdx.x;
  int g = bid / GSPLIT;
  int s = bid % GSPLIT;
  int chunk = (N + GSPLIT - 1) / GSPLIT;
  int start = s * chunk;
  int end = start + chunk; if (end > N) end = N;
  int lane = threadIdx.x;
  float x0 = gtb[g * 4 + 0], y0 = gtb[g * 4 + 1];
  float x1 = gtb[g * 4 + 2], y1 = gtb[g * 4 + 3];
  float gcx = (x0 + x1) * 0.5f, gcy = (y0 + y1) * 0.5f;
  const float4* pri4 = reinterpret_cast<const float4*>(priors);
  int* gl = gateList + (size_t)g * GCAP;

  for (int nb = start; nb < end; nb += ATPB) {
    int n = nb + lane;
    bool ing = false, inc = false;
    if (n < end) {
      float4 pv = pri4[n];
      float px = pv.x, py = pv.y, sx = pv.z, sy = pv.w;
      float l_ = px - x0, t_ = py - y0, r_ = x1 - px, b_ = y1 - py;
      ing = fminf(fminf(l_, t_), fminf(r_, b_)) > 0.0f;
      float cl = px - (gcx - 2.5f * sx), ct = py - (gcy - 2.5f * sy);
      float cr = (gcx + 2.5f * sx) - px, cb = (gcy + 2.5f * sy) - py;
      inc = fminf(fminf(cl, ct), fminf(cr, cb)) > 0.0f;
      if (ing || inc) validArr[n] = 1;  // benign same-value race across g
    }
    bool gated = ing && inc;
    u64 mask = __ballot(gated);
    int cnt = __popcll(mask);
    int base = 0;
    if (lane == 0 && cnt > 0) base = atomicAdd(&gateCnt[g], cnt);
    base = __shfl(base, 0);
    if (gated) {
      int prefix = __popcll(mask & ((1ull << lane) - 1ull));
      int slot = base + prefix;
      if (slot < GCAP) gl[slot] = n;
      else flags[g] = 1;  // overflow -> exact full-scan fallback for this g
    }
  }
}

// Kernel 3: ONE WAVE per (g, split), ISPLIT=64. Only iv[10] live; zero-init
// (iou>=0; zero-pad sum-invariant) so ~95% of zero-iou pairs skip the insert.
__global__ __launch_bounds__(ATPB) void k_iou_part(
    const float* dec, const u8* validArr, const float* gtb,
    float* iouV, int N, int G)
{
  int bid = blockIdx.x;
  int g = bid / ISPLIT;
  int s = bid % ISPLIT;
  int chunk = (N + ISPLIT - 1) / ISPLIT;
  int start = s * chunk;
  int end = start + chunk; if (end > N) end = N;
  int tid = threadIdx.x;
  float bx0 = gtb[g * 4 + 0];
  float by0 = gtb[g * 4 + 1];
  float bx1 = gtb[g * 4 + 2];
  float by1 = gtb[g * 4 + 3];

  float iv[KTOP];
#pragma unroll
  for (int j = 0; j < KTOP; ++j) iv[j] = 0.0f;

  const float4* dec4 = reinterpret_cast<const float4*>(dec);
  for (int n = start + tid; n < end; n += ATPB) {
    float4 dvb = dec4[n];
    float iou = f_iou(dvb.x, dvb.y, dvb.z, dvb.w, bx0, by0, bx1, by1);
    if (!validArr[n]) iou = 0.0f;
    if (iou > iv[KTOP - 1]) {
      float cu = iou;
#pragma unroll
      for (int j = 0; j < KTOP; ++j) {
        if (cu > iv[j]) { float tv = iv[j]; iv[j] = cu; cu = tv; }
      }
    }
  }

  // wave tournament: 10 rounds max + owner pop (values only)
#pragma unroll
  for (int r = 0; r < KTOP; ++r) {
    float v = iv[0]; int owner = tid;
#pragma unroll
    for (int off = 32; off > 0; off >>= 1) {
      float v2 = __shfl_down(v, off);
      int o2 = __shfl_down(owner, off);
      if (v2 > v || (v2 == v && o2 < owner)) { v = v2; owner = o2; }
    }
    float wv = __shfl(v, 0);
    int wo = __shfl(owner, 0);
    if (tid == 0) iouV[bid * KTOP + r] = wv;
    if (tid == wo) {
#pragma unroll
      for (int j = 0; j < KTOP - 1; ++j) iv[j] = iv[j + 1];
      iv[KTOP - 1] = 0.0f;
    }
  }
}

// Kernel 4: one 64-thread block per g. (a) top-10 of ISPLIT*10 iou values ->
// dynamic_k; (b) cost eval over the gated candidates only (gated cost is
// strictly below any ungated/invalid cost, so when gateCnt>=10 the global
// top-10 == gated top-10). Lexicographic (cost,n) -> order-independent.
__global__ __launch_bounds__(ATPB) void k_merge(
    const float* iouV, const int* gateCnt, const int* gateList, const int* flags,
    const float* pred, const float* dec, const float* sumL1,
    const int* gtl, const float* gtb,
    u32* packed, int* dkArr, int G, int N, int C)
{
  int g = blockIdx.x;
  int tid = threadIdx.x;
  int base = g * ISPLIT * KTOP;
  const int TOT = ISPLIT * KTOP;            // 640
  const int PER = TOT / ATPB;               // 10

  float il[PER];
#pragma unroll
  for (int k = 0; k < PER; ++k) il[k] = 0.0f;
#pragma unroll
  for (int k = 0; k < PER; ++k) {
    float v = iouV[base + tid + k * ATPB];
    if (v > il[PER - 1]) {
#pragma unroll
      for (int j = 0; j < PER; ++j) {
        if (v > il[j]) { float tv = il[j]; il[j] = v; v = tv; }
      }
    }
  }
  float rv[KTOP];
#pragma unroll
  for (int r = 0; r < KTOP; ++r) {
    float v = il[0]; int owner = tid;
#pragma unroll
    for (int off = 32; off > 0; off >>= 1) {
      float v2 = __shfl_down(v, off);
      int o2 = __shfl_down(owner, off);
      if (v2 > v || (v2 == v && o2 < owner)) { v = v2; owner = o2; }
    }
    float wv = __shfl(v, 0);
    int wo = __shfl(owner, 0);
    rv[r] = wv;
    if (tid == wo) {
#pragma unroll
      for (int j = 0; j < PER - 1; ++j) il[j] = il[j + 1];
      il[PER - 1] = 0.0f;
    }
  }
  // numpy pairwise order for a 10-element sum (all lanes identical)
  float s8 = ((rv[0] + rv[1]) + (rv[2] + rv[3])) + ((rv[4] + rv[5]) + (rv[6] + rv[7]));
  s8 += rv[8];
  s8 += rv[9];
  int dk = (int)s8;  // trunc toward zero == astype(int32)
  if (dk < 1) dk = 1;
  if (dk > KTOP) dk = KTOP;
  if (tid == 0) dkArr[g] = dk;

  int cnt = gateCnt[g];
  if (flags[g] || cnt < KTOP) return;  // exact fallback handles this g

  float bx0 = gtb[g * 4 + 0];
  float by0 = gtb[g * 4 + 1];
  float bx1 = gtb[g * 4 + 2];
  float by1 = gtb[g * 4 + 3];
  int lab = gtl[g];
  if (lab < 0) lab = 0;
  if (lab >= C) lab = C - 1;

  float cv[KTOP]; int ci[KTOP];
#pragma unroll
  for (int j = 0; j < KTOP; ++j) { cv[j] = 1e30f; ci[j] = INT_MAX; }
  const float4* dec4 = reinterpret_cast<const float4*>(dec);
  const int* gl = gateList + (size_t)g * GCAP;

  for (int i = tid; i < cnt; i += ATPB) {
    int n = gl[i];
    float4 dvb = dec4[n];
    float iou = f_iou(dvb.x, dvb.y, dvb.z, dvb.w, bx0, by0, bx1, by1);
    float dv = f_dv(pred[(size_t)n * C + lab]);
    float cls = dv - sumL1[n];
    float icost = -logf(iou + 1e-7f);
    float c = (cls * 1.0f + icost * 3.0f) + 0.0f;  // gate true -> +0.0 exactly
    // lexicographic (c, n) insert — canonical regardless of arrival order
    bool ins = (c < cv[KTOP - 1]) || (c == cv[KTOP - 1] && n < ci[KTOP - 1]);
    if (ins) {
      float cu = c; int cui = n;
#pragma unroll
      for (int j = 0; j < KTOP; ++j) {
        bool lt = (cu < cv[j]) || (cu == cv[j] && cui < ci[j]);
        if (lt) { float tv = cv[j]; int ti = ci[j]; cv[j] = cu; ci[j] = cui; cu = tv; cui = ti; }
      }
    }
  }

  for (int r = 0; r < KTOP; ++r) {
    float v = cv[0]; int idx = ci[0];
#pragma unroll
    for (int off = 32; off > 0; off >>= 1) {
      float v2 = __shfl_down(v, off);
      int i2 = __shfl_down(idx, off);
      if (v2 < v || (v2 == v && i2 < idx)) { v = v2; idx = i2; }
    }
    int wi = __shfl(idx, 0);
    if (r < dk && tid == 0 && wi >= 0 && wi < N) {
      // count in high 16 bits; sum of g in low 16 (exact g when count==1)
      atomicAdd(&packed[wi], (1u << 16) | (u32)g);
    }
    if (ci[0] == wi) {  // candidate n unique per g -> exactly one lane pops
#pragma unroll
      for (int j = 0; j < KTOP - 1; ++j) { cv[j] = cv[j + 1]; ci[j] = ci[j + 1]; }
      cv[KTOP - 1] = 1e30f; ci[KTOP - 1] = INT_MAX;
    }
    if (r + 1 >= dk) break;
  }
}

// Exact full-scan fallback for flagged g (gateCnt<10 or overflow) — rare.
__global__ __launch_bounds__(TPB) void k_fb_scan(
    const float* pred, const float* priors, const float* dec, const float* gtb,
    const int* gtl, const float* sumL1, const u8* validArr,
    const int* gateCnt, const int* flags, const int* dkArr,
    u32* packed, int N, int G, int C)
{
  int g = blockIdx.x;
  if (!(flags[g] || gateCnt[g] < KTOP)) return;
  int tid = threadIdx.x;
  float bx0 = gtb[g * 4 + 0];
  float by0 = gtb[g * 4 + 1];
  float bx1 = gtb[g * 4 + 2];
  float by1 = gtb[g * 4 + 3];
  int lab = gtl[g];
  if (lab < 0) lab = 0;
  if (lab >= C) lab = C - 1;

  float cv[KTOP]; int ci[KTOP];
  for (int j = 0; j < KTOP; ++j) { cv[j] = 1e30f; ci[j] = INT_MAX; }
  const float4* dec4 = reinterpret_cast<const float4*>(dec);
  const float4* pri4 = reinterpret_cast<const float4*>(priors);

  for (int n = tid; n < N; n += TPB) {
    float4 dvb = dec4[n];
    int vld = validArr[n];
    float iou = f_iou(dvb.x, dvb.y, dvb.z, dvb.w, bx0, by0, bx1, by1);
    if (!vld) iou = 0.0f;
    float dv = f_dv(pred[(size_t)n * C + lab]);
    float4 pv = pri4[n];
    float c = f_cost(iou, dv, sumL1[n], pv.x, pv.y, pv.z, pv.w, bx0, by0, bx1, by1, vld);
    bool ins = (c < cv[KTOP - 1]) || (c == cv[KTOP - 1] && n < ci[KTOP - 1]);
    if (ins) {
      float cu = c; int cui = n;
      for (int j = 0; j < KTOP; ++j) {
        bool lt = (cu < cv[j]) || (cu == cv[j] && cui < ci[j]);
        if (lt) { float tv = cv[j]; int ti = ci[j]; cv[j] = cu; ci[j] = cui; cu = tv; cui = ti; }
      }
    }
  }

  __shared__ float sv[TPB];
  __shared__ int   si[TPB];
  int dk = dkArr[g];
  for (int r = 0; r < KTOP; ++r) {
    sv[tid] = cv[0]; si[tid] = ci[0];
    __syncthreads();
    for (int st = TPB / 2; st > 0; st >>= 1) {
      if (tid < st) {
        float v2 = sv[tid + st]; int i2 = si[tid + st];
        float v1 = sv[tid];      int i1 = si[tid];
        if (v2 < v1 || (v2 == v1 && i2 < i1)) { sv[tid] = v2; si[tid] = i2; }
      }
      __syncthreads();
    }
    int wi = si[0];
    if (r < dk && tid == 0 && wi >= 0 && wi < N)
      atomicAdd(&packed[wi], (1u << 16) | (u32)g);
    __syncthreads();
    if (ci[0] == wi) {
      for (int j = 0; j < KTOP - 1; ++j) { cv[j] = cv[j + 1]; ci[j] = ci[j + 1]; }
      cv[KTOP - 1] = 1e30f; ci[KTOP - 1] = INT_MAX;
    }
  }
}

// Kernel 5 stage A: resolve cnt==0/1 inline, queue cnt>1 into worklist.
__global__ __launch_bounds__(TPB) void k_final(
    const float* dec, const float* gtb, const u8* validArr, const u32* packed,
    int* mlist, int* mcnt,
    float* out, int N, int G, int Nout)
{
  __shared__ float sg[MAXG * 4];
  for (int i = threadIdx.x; i < G * 4; i += blockDim.x) sg[i] = gtb[i];
  __syncthreads();
  int n = blockIdx.x * blockDim.x + threadIdx.x;
  if (n >= N || n >= Nout) return;
  u32 pk = packed[n];
  int cnt = (int)(pk >> 16);
  float o0 = 0.0f, o1 = -1.0f, o2 = -100000.0f;
  if (cnt > 1) {
    int idx = atomicAdd(mcnt, 1);
    if (idx < MAXMULTI) mlist[idx] = n;
    // outputs for this n written by k_multi (later kernel, no race)
  }
  if (cnt == 1) {
    int g = (int)(pk & 0xFFFFu);
    if (g < 0) g = 0;
    if (g >= G) g = G - 1;
    const float4 dv = reinterpret_cast<const float4*>(dec)[n];
    float x0 = sg[g * 4 + 0], y0 = sg[g * 4 + 1], x1 = sg[g * 4 + 2], y1 = sg[g * 4 + 3];
    float iou = f_iou(dv.x, dv.y, dv.z, dv.w, x0, y0, x1, y1);
    if (!validArr[n]) iou = 0.0f;
    o0 = (float)g; o1 = 1.0f; o2 = iou;
  }
  out[n]            = o0;
  out[Nout + n]     = o1;
  out[2 * Nout + n] = o2;
}

// Kernel 5 stage B: one 128-thread block per multi anchor (grid-stride).
// Lane gg computes cost(n,gg); LDS argmin tree, first-min tie == np.argmin.
#define MTPB 128
__global__ __launch_bounds__(MTPB) void k_multi(
    const float* pred, const float* priors, const float* dec,
    const float* gtb, const int* gtl, const float* sumL1, const u8* validArr,
    const int* mlist, const int* mcnt,
    float* out, int N, int G, int C, int Nout)
{
  __shared__ float rv[MTPB];
  __shared__ int   rg[MTPB];
  int tid = threadIdx.x;
  int total = *mcnt;
  if (total > MAXMULTI) total = MAXMULTI;
  for (int w = blockIdx.x; w < total; w += gridDim.x) {
    int n = mlist[w];
    const float4 dvb = reinterpret_cast<const float4*>(dec)[n];
    const float4 pv  = reinterpret_cast<const float4*>(priors)[n];
    float s1 = sumL1[n];
    int vld = validArr[n];
    float best = 1e30f; int bg = INT_MAX;
    for (int gg = tid; gg < G; gg += MTPB) {
      float x0 = gtb[gg * 4 + 0], y0 = gtb[gg * 4 + 1];
      float x1 = gtb[gg * 4 + 2], y1 = gtb[gg * 4 + 3];
      float iou = f_iou(dvb.x, dvb.y, dvb.z, dvb.w, x0, y0, x1, y1);
      if (!vld) iou = 0.0f;
      int lb = gtl[gg];
      if (lb < 0) lb = 0;
      if (lb >= C) lb = C - 1;
      float dv = f_dv(pred[(size_t)n * C + lb]);
      float c = f_cost(iou, dv, s1, pv.x, pv.y, pv.z, pv.w, x0, y0, x1, y1, vld);
      if (c < best || (c == best && gg < bg)) { best = c; bg = gg; }
    }
    rv[tid] = best; rg[tid] = bg;
    __syncthreads();
    for (int st = MTPB / 2; st > 0; st >>= 1) {
      if (tid < st) {
        float v2 = rv[tid + st]; int g2 = rg[tid + st];
        float v1 = rv[tid];      int g1 = rg[tid];
        if (v2 < v1 || (v2 == v1 && g2 < g1)) { rv[tid] = v2; rg[tid] = g2; }
      }
      __syncthreads();
    }
    if (tid == 0) {
      int g = rg[0];
      if (g < 0 || g >= G) g = 0;
      float x0 = gtb[g * 4 + 0], y0 = gtb[g * 4 + 1];
      float x1 = gtb[g * 4 + 2], y1 = gtb[g * 4 + 3];
      float iou = f_iou(dvb.x, dvb.y, dvb.z, dvb.w, x0, y0, x1, y1);
      if (!vld) iou = 0.0f;
      out[n]            = (float)g;
      out[Nout + n]     = 1.0f;
      out[2 * Nout + n] = iou;
    }
    __syncthreads();  // protect rv/rg before next worklist item
  }
}

extern "C" void kernel_launch(void* const* d_in, const int* in_sizes, int n_in,
                              void* d_out, int out_size, void* d_ws, size_t ws_size,
                              hipStream_t stream) {
  const float* pred   = (const float*)d_in[0];  // (N,C) f32
  const float* priors = (const float*)d_in[1];  // (N,4) f32
  const float* dec    = (const float*)d_in[2];  // (N,4) f32
  const float* gtb    = (const float*)d_in[3];  // (G,4) f32
  const int*   gtl    = (const int*)d_in[4];    // (G,)  int32
  int N = in_sizes[2] / 4;
  int G = in_sizes[3] / 4;
  if (G > MAXG) G = MAXG;
  int C = in_sizes[0] / N;
  int Nout = out_size / 3;
  float* out = (float*)d_out;

  // ws layout (16B-aligned blocks). Zero-region [offZero, offValid+N) covers
  // gateCnt | flags | mcnt | pad | validArr in ONE memset.
  size_t offPacked = 0;
  size_t offSum    = offPacked + (size_t)N * 4;
  size_t offZero   = (offSum + (size_t)N * 4 + 15) & ~(size_t)15;
  size_t offFlags  = offZero + (size_t)G * 4;
  size_t offMcnt   = offFlags + (size_t)G * 4;
  size_t offValid  = (offMcnt + 4 + 15) & ~(size_t)15;
  size_t offMlist  = (offValid + (size_t)N + 15) & ~(size_t)15;
  size_t offDk     = offMlist + (size_t)MAXMULTI * 4;
  size_t offGlist  = (offDk + (size_t)G * 4 + 15) & ~(size_t)15;
  size_t offIouV   = offGlist + (size_t)G * GCAP * 4;
  size_t need      = offIouV + (size_t)G * ISPLIT * KTOP * 4;

  dim3 b(TPB);
  int nblk = (N + TPB - 1) / TPB;
  int oblk = (Nout + TPB - 1) / TPB;
  if (ws_size < need || d_ws == nullptr) {
    k_fallback<<<oblk, b, 0, stream>>>(out, Nout);  // sentinel: -70000 at out2
    return;
  }
  char* wsb = (char*)d_ws;
  u32* packed   = (u32*)(wsb + offPacked);
  float* sumL1  = (float*)(wsb + offSum);
  int* gateCnt  = (int*)(wsb + offZero);
  int* flags    = (int*)(wsb + offFlags);
  int* mcnt     = (int*)(wsb + offMcnt);
  u8* validArr  = (u8*)(wsb + offValid);
  int* mlist    = (int*)(wsb + offMlist);
  int* dkArr    = (int*)(wsb + offDk);
  int* gateList = (int*)(wsb + offGlist);
  float* iouV   = (float*)(wsb + offIouV);

  // one memset: gateCnt+flags+mcnt+pad+validArr
  hipMemsetAsync(wsb + offZero, 0, offValid + (size_t)N - offZero, stream);

  int sumblk = ((N * 8) + TPB - 1) / TPB;
  k_sum<<<sumblk, b, 0, stream>>>(pred, sumL1, packed, N, C);
  k_gate<<<G * GSPLIT, dim3(ATPB), 0, stream>>>(priors, gtb, validArr, gateCnt, gateList, flags, N, G);
  k_iou_part<<<G * ISPLIT, dim3(ATPB), 0, stream>>>(dec, validArr, gtb, iouV, N, G);
  k_merge<<<G, dim3(ATPB), 0, stream>>>(iouV, gateCnt, gateList, flags,
                                        pred, dec, sumL1, gtl, gtb,
                                        packed, dkArr, G, N, C);
  k_fb_scan<<<G, b, 0, stream>>>(pred, priors, dec, gtb, gtl, sumL1, validArr,
                                 gateCnt, flags, dkArr, packed, N, G, C);
  k_final<<<nblk, b, 0, stream>>>(dec, gtb, validArr, packed, mlist, mcnt, out, N, G, Nout);
  k_multi<<<256, dim3(MTPB), 0, stream>>>(pred, priors, dec, gtb, gtl, sumL1, validArr,
                                          mlist, mcnt, out, N, G, C, Nout);
}

// Round 11
// 127.143 us; speedup vs baseline: 1.4883x; 1.3659x over previous
//
#include <hip/hip_runtime.h>
#include <math.h>
#include <limits.h>

// Match numpy op-for-op: no fma contraction anywhere.
#pragma clang fp contract(off)

#define TPB 256
#define ATPB 64
#define KTOP 10
#define ISPLIT 64
#define GSPLIT 8
#define GCAP 4096
#define CHUNKCAP 4224
#define MAXG 512
#define MAXMULTI 4096

typedef unsigned int u32;
typedef unsigned long long u64;
typedef unsigned char u8;

// pairwise IoU, identical op order to the numpy reference
__device__ __forceinline__ float f_iou(float ax0, float ay0, float ax1, float ay1,
                                       float bx0, float by0, float bx1, float by1) {
  float tlx = fmaxf(ax0, bx0);
  float tly = fmaxf(ay0, by0);
  float brx = fminf(ax1, bx1);
  float bry = fminf(ay1, by1);
  float w = fmaxf(brx - tlx, 0.0f);
  float h = fmaxf(bry - tly, 0.0f);
  float inter = w * h;
  float aa = fmaxf(ax1 - ax0, 0.0f) * fmaxf(ay1 - ay0, 0.0f);
  float ab = fmaxf(bx1 - bx0, 0.0f) * fmaxf(by1 - by0, 0.0f);
  float uni = aa + ab - inter;
  return inter / fmaxf(uni, 1e-7f);
}

// dv = -(L - L1), exact expression tree of the reference cls numerator
__device__ __forceinline__ float f_dv(float p) {
  float L  = fmaxf(logf(p), -100.0f);
  float L1 = fmaxf(log1pf(-p), -100.0f);
  return -(L - L1);
}

// full cost(n,g); identical op order to reference (cls = dv - sumL1).
__device__ __forceinline__ float f_cost(float iou_masked, float dv, float sumL1v,
                                        float px, float py, float sx, float sy,
                                        float bx0, float by0, float bx1, float by1,
                                        int vld) {
  if (!vld) return 100000000.0f;  // BIG
  float cls = dv - sumL1v;
  float l_ = px - bx0, t_ = py - by0, r_ = bx1 - px, b_ = by1 - py;
  bool ing = fminf(fminf(l_, t_), fminf(r_, b_)) > 0.0f;
  float gcx = (bx0 + bx1) * 0.5f;
  float gcy = (by0 + by1) * 0.5f;
  float cl = px - (gcx - 2.5f * sx);
  float ct = py - (gcy - 2.5f * sy);
  float cr = (gcx + 2.5f * sx) - px;
  float cb = (gcy + 2.5f * sy) - py;
  bool inc = fminf(fminf(cl, ct), fminf(cr, cb)) > 0.0f;
  float icost = -logf(iou_masked + 1e-7f);
  return (cls * 1.0f + icost * 3.0f) + ((ing && inc) ? 0.0f : 100000.0f);
}

// Fallback: distinct sentinel so a too-small workspace is diagnosable.
__global__ __launch_bounds__(TPB) void k_fallback(float* out, int Nout) {
  int n = blockIdx.x * blockDim.x + threadIdx.x;
  if (n >= Nout) return;
  out[n] = 0.0f;
  out[Nout + n] = -1.0f;
  out[2 * Nout + n] = -70000.0f;
}

// Phase 1 (fused): blocks [0, sumBlocks) do per-anchor sumL1 (+ packed=0);
// blocks [sumBlocks, ...) do gating for one (g, split): gate test per pair,
// valid[n] store (benign same-value race), gated indices buffered in LDS
// (wave-ballot + LDS-atomic), ONE global atomic per block, bulk copy out.
__global__ __launch_bounds__(TPB) void k_phase1(
    const float* pred, const float* priors, const float* gtb,
    float* sumL1, u32* packed, u8* validArr,
    int* gateCnt, int* gateList, int* flags,
    int N, int G, int C, int sumBlocks)
{
  __shared__ int lbuf[CHUNKCAP];
  __shared__ int lcnt;
  __shared__ int gbase;

  if ((int)blockIdx.x < sumBlocks) {
    // ---- sum role: 8 lanes per anchor, numpy 8-accumulator pairwise order ----
    int t = blockIdx.x * TPB + threadIdx.x;
    int n = t >> 3;
    int j = t & 7;
    if (n >= N) return;
    const float* pr = pred + (size_t)n * C;
    int lim = C - (C % 8);
    float r = 0.0f;
    for (int i = j; i < lim; i += 8) r += fmaxf(log1pf(-pr[i]), -100.0f);
    r += __shfl_down(r, 1, 8);
    r += __shfl_down(r, 2, 8);
    r += __shfl_down(r, 4, 8);
    if (j == 0) {
      for (int i = lim; i < C; ++i) r += fmaxf(log1pf(-pr[i]), -100.0f);
      sumL1[n] = r;
      packed[n] = 0;  // ws re-poisoned every launch — must re-zero
    }
    return;
  }

  // ---- gate role ----
  int bid = blockIdx.x - sumBlocks;
  int g = bid / GSPLIT;
  int s = bid % GSPLIT;
  int chunk = (N + GSPLIT - 1) / GSPLIT;
  int start = s * chunk;
  int end = start + chunk; if (end > N) end = N;
  int lane = threadIdx.x & 63;

  if (threadIdx.x == 0) lcnt = 0;
  __syncthreads();

  float x0 = gtb[g * 4 + 0], y0 = gtb[g * 4 + 1];
  float x1 = gtb[g * 4 + 2], y1 = gtb[g * 4 + 3];
  float gcx = (x0 + x1) * 0.5f, gcy = (y0 + y1) * 0.5f;
  const float4* pri4 = reinterpret_cast<const float4*>(priors);

  for (int nb = start; nb < end; nb += TPB) {
    int n = nb + threadIdx.x;
    bool gated = false;
    if (n < end) {
      float4 pv = pri4[n];
      float px = pv.x, py = pv.y, sx = pv.z, sy = pv.w;
      float l_ = px - x0, t_ = py - y0, r_ = x1 - px, b_ = y1 - py;
      bool ing = fminf(fminf(l_, t_), fminf(r_, b_)) > 0.0f;
      float cl = px - (gcx - 2.5f * sx), ct = py - (gcy - 2.5f * sy);
      float cr = (gcx + 2.5f * sx) - px, cb = (gcy + 2.5f * sy) - py;
      bool inc = fminf(fminf(cl, ct), fminf(cr, cb)) > 0.0f;
      if (ing || inc) validArr[n] = 1;  // benign same-value race across g
      gated = ing && inc;
    }
    u64 mask = __ballot(gated);
    int wcnt = __popcll(mask);
    int wbase = 0;
    if (lane == 0 && wcnt > 0) wbase = atomicAdd(&lcnt, wcnt);  // LDS atomic
    wbase = __shfl(wbase, 0);
    if (gated) {
      int p = __popcll(mask & ((1ull << lane) - 1ull));
      lbuf[wbase + p] = n;  // lcnt <= chunk <= CHUNKCAP by construction
    }
  }
  __syncthreads();
  int total = lcnt;
  if (threadIdx.x == 0 && total > 0) gbase = atomicAdd(&gateCnt[g], total);
  __syncthreads();
  if (total > 0) {
    int base = gbase;
    int* gl = gateList + (size_t)g * GCAP;
    for (int i = threadIdx.x; i < total; i += TPB) {
      int slot = base + i;
      if (slot < GCAP) gl[slot] = lbuf[i];
      else flags[g] = 1;  // overflow -> exact full-scan fallback for this g
    }
  }
}

// Kernel 2: ONE WAVE per (g, split), ISPLIT=64. Only iv[10] live; zero-init
// (iou>=0; zero-pad sum-invariant) so ~95% of zero-iou pairs skip the insert.
__global__ __launch_bounds__(ATPB) void k_iou_part(
    const float* dec, const u8* validArr, const float* gtb,
    float* iouV, int N, int G)
{
  int bid = blockIdx.x;
  int g = bid / ISPLIT;
  int s = bid % ISPLIT;
  int chunk = (N + ISPLIT - 1) / ISPLIT;
  int start = s * chunk;
  int end = start + chunk; if (end > N) end = N;
  int tid = threadIdx.x;
  float bx0 = gtb[g * 4 + 0];
  float by0 = gtb[g * 4 + 1];
  float bx1 = gtb[g * 4 + 2];
  float by1 = gtb[g * 4 + 3];

  float iv[KTOP];
#pragma unroll
  for (int j = 0; j < KTOP; ++j) iv[j] = 0.0f;

  const float4* dec4 = reinterpret_cast<const float4*>(dec);
  for (int n = start + tid; n < end; n += ATPB) {
    float4 dvb = dec4[n];
    float iou = f_iou(dvb.x, dvb.y, dvb.z, dvb.w, bx0, by0, bx1, by1);
    if (!validArr[n]) iou = 0.0f;
    if (iou > iv[KTOP - 1]) {
      float cu = iou;
#pragma unroll
      for (int j = 0; j < KTOP; ++j) {
        if (cu > iv[j]) { float tv = iv[j]; iv[j] = cu; cu = tv; }
      }
    }
  }

  // wave tournament: 10 rounds max + owner pop (values only)
#pragma unroll
  for (int r = 0; r < KTOP; ++r) {
    float v = iv[0]; int owner = tid;
#pragma unroll
    for (int off = 32; off > 0; off >>= 1) {
      float v2 = __shfl_down(v, off);
      int o2 = __shfl_down(owner, off);
      if (v2 > v || (v2 == v && o2 < owner)) { v = v2; owner = o2; }
    }
    float wv = __shfl(v, 0);
    int wo = __shfl(owner, 0);
    if (tid == 0) iouV[bid * KTOP + r] = wv;
    if (tid == wo) {
#pragma unroll
      for (int j = 0; j < KTOP - 1; ++j) iv[j] = iv[j + 1];
      iv[KTOP - 1] = 0.0f;
    }
  }
}

// Kernel 3 (fused merge + fallback): one WAVE per g.
// (a) dynamic_k from iouV top-10; (b) cost top-10: gated-only scan when
// gateCnt>=10 and no overflow (gated cost strictly below ungated/invalid),
// else exact full scan. Lexicographic (cost,n) -> order-independent & stable.
__global__ __launch_bounds__(ATPB) void k_merge(
    const float* iouV, const int* gateCnt, const int* gateList, const int* flags,
    const float* pred, const float* priors, const float* dec, const float* sumL1,
    const u8* validArr, const int* gtl, const float* gtb,
    u32* packed, int G, int N, int C)
{
  int g = blockIdx.x;
  int tid = threadIdx.x;
  int base = g * ISPLIT * KTOP;
  const int TOT = ISPLIT * KTOP;            // 640
  const int PER = TOT / ATPB;               // 10

  // --- dynamic_k from iou top-10 of TOT values (zero-padded; sum invariant) ---
  float il[PER];
#pragma unroll
  for (int k = 0; k < PER; ++k) il[k] = 0.0f;
#pragma unroll
  for (int k = 0; k < PER; ++k) {
    float v = iouV[base + tid + k * ATPB];
    if (v > il[PER - 1]) {
#pragma unroll
      for (int j = 0; j < PER; ++j) {
        if (v > il[j]) { float tv = il[j]; il[j] = v; v = tv; }
      }
    }
  }
  float rv[KTOP];
#pragma unroll
  for (int r = 0; r < KTOP; ++r) {
    float v = il[0]; int owner = tid;
#pragma unroll
    for (int off = 32; off > 0; off >>= 1) {
      float v2 = __shfl_down(v, off);
      int o2 = __shfl_down(owner, off);
      if (v2 > v || (v2 == v && o2 < owner)) { v = v2; owner = o2; }
    }
    float wv = __shfl(v, 0);
    int wo = __shfl(owner, 0);
    rv[r] = wv;
    if (tid == wo) {
#pragma unroll
      for (int j = 0; j < PER - 1; ++j) il[j] = il[j + 1];
      il[PER - 1] = 0.0f;
    }
  }
  // numpy pairwise order for a 10-element sum (all lanes identical)
  float s8 = ((rv[0] + rv[1]) + (rv[2] + rv[3])) + ((rv[4] + rv[5]) + (rv[6] + rv[7]));
  s8 += rv[8];
  s8 += rv[9];
  int dk = (int)s8;  // trunc toward zero == astype(int32)
  if (dk < 1) dk = 1;
  if (dk > KTOP) dk = KTOP;

  float bx0 = gtb[g * 4 + 0];
  float by0 = gtb[g * 4 + 1];
  float bx1 = gtb[g * 4 + 2];
  float by1 = gtb[g * 4 + 3];
  int lab = gtl[g];
  if (lab < 0) lab = 0;
  if (lab >= C) lab = C - 1;

  float cv[KTOP]; int ci[KTOP];
#pragma unroll
  for (int j = 0; j < KTOP; ++j) { cv[j] = 1e30f; ci[j] = INT_MAX; }
  const float4* dec4 = reinterpret_cast<const float4*>(dec);

  int cnt = gateCnt[g];
  if (!flags[g] && cnt >= KTOP) {
    // fast path: gated candidates only (penalty term == +0.0f exactly)
    const int* gl = gateList + (size_t)g * GCAP;
    for (int i = tid; i < cnt; i += ATPB) {
      int n = gl[i];
      float4 dvb = dec4[n];
      float iou = f_iou(dvb.x, dvb.y, dvb.z, dvb.w, bx0, by0, bx1, by1);
      float dv = f_dv(pred[(size_t)n * C + lab]);
      float cls = dv - sumL1[n];
      float icost = -logf(iou + 1e-7f);
      float c = (cls * 1.0f + icost * 3.0f) + 0.0f;
      bool ins = (c < cv[KTOP - 1]) || (c == cv[KTOP - 1] && n < ci[KTOP - 1]);
      if (ins) {
        float cu = c; int cui = n;
#pragma unroll
        for (int j = 0; j < KTOP; ++j) {
          bool lt = (cu < cv[j]) || (cu == cv[j] && cui < ci[j]);
          if (lt) { float tv = cv[j]; int ti = ci[j]; cv[j] = cu; ci[j] = cui; cu = tv; cui = ti; }
        }
      }
    }
  } else {
    // exact full scan (rare: gateCnt<10 or overflow)
    const float4* pri4 = reinterpret_cast<const float4*>(priors);
    for (int n = tid; n < N; n += ATPB) {
      float4 dvb = dec4[n];
      int vld = validArr[n];
      float iou = f_iou(dvb.x, dvb.y, dvb.z, dvb.w, bx0, by0, bx1, by1);
      if (!vld) iou = 0.0f;
      float dv = f_dv(pred[(size_t)n * C + lab]);
      float4 pv = pri4[n];
      float c = f_cost(iou, dv, sumL1[n], pv.x, pv.y, pv.z, pv.w, bx0, by0, bx1, by1, vld);
      bool ins = (c < cv[KTOP - 1]) || (c == cv[KTOP - 1] && n < ci[KTOP - 1]);
      if (ins) {
        float cu = c; int cui = n;
#pragma unroll
        for (int j = 0; j < KTOP; ++j) {
          bool lt = (cu < cv[j]) || (cu == cv[j] && cui < ci[j]);
          if (lt) { float tv = cv[j]; int ti = ci[j]; cv[j] = cu; ci[j] = cui; cu = tv; cui = ti; }
        }
      }
    }
  }

  // wave tournament: dk rounds of lexicographic min, scatter
  for (int r = 0; r < KTOP; ++r) {
    float v = cv[0]; int idx = ci[0];
#pragma unroll
    for (int off = 32; off > 0; off >>= 1) {
      float v2 = __shfl_down(v, off);
      int i2 = __shfl_down(idx, off);
      if (v2 < v || (v2 == v && i2 < idx)) { v = v2; idx = i2; }
    }
    int wi = __shfl(idx, 0);
    if (r < dk && tid == 0 && wi >= 0 && wi < N) {
      // count in high 16 bits; sum of g in low 16 (exact g when count==1)
      atomicAdd(&packed[wi], (1u << 16) | (u32)g);
    }
    if (ci[0] == wi) {  // candidate n unique per g -> exactly one lane pops
#pragma unroll
      for (int j = 0; j < KTOP - 1; ++j) { cv[j] = cv[j + 1]; ci[j] = ci[j + 1]; }
      cv[KTOP - 1] = 1e30f; ci[KTOP - 1] = INT_MAX;
    }
    if (r + 1 >= dk) break;
  }
}

// Kernel 4 stage A: resolve cnt==0/1 inline, queue cnt>1 into worklist.
__global__ __launch_bounds__(TPB) void k_final(
    const float* dec, const float* gtb, const u8* validArr, const u32* packed,
    int* mlist, int* mcnt,
    float* out, int N, int G, int Nout)
{
  __shared__ float sg[MAXG * 4];
  for (int i = threadIdx.x; i < G * 4; i += blockDim.x) sg[i] = gtb[i];
  __syncthreads();
  int n = blockIdx.x * blockDim.x + threadIdx.x;
  if (n >= N || n >= Nout) return;
  u32 pk = packed[n];
  int cnt = (int)(pk >> 16);
  float o0 = 0.0f, o1 = -1.0f, o2 = -100000.0f;
  if (cnt > 1) {
    int idx = atomicAdd(mcnt, 1);
    if (idx < MAXMULTI) mlist[idx] = n;
    // outputs for this n written by k_multi (later kernel, no race)
  }
  if (cnt == 1) {
    int g = (int)(pk & 0xFFFFu);
    if (g < 0) g = 0;
    if (g >= G) g = G - 1;
    const float4 dv = reinterpret_cast<const float4*>(dec)[n];
    float x0 = sg[g * 4 + 0], y0 = sg[g * 4 + 1], x1 = sg[g * 4 + 2], y1 = sg[g * 4 + 3];
    float iou = f_iou(dv.x, dv.y, dv.z, dv.w, x0, y0, x1, y1);
    if (!validArr[n]) iou = 0.0f;
    o0 = (float)g; o1 = 1.0f; o2 = iou;
  }
  out[n]            = o0;
  out[Nout + n]     = o1;
  out[2 * Nout + n] = o2;
}

// Kernel 4 stage B: one 128-thread block per multi anchor (grid-stride).
// Lane gg computes cost(n,gg); LDS argmin tree, first-min tie == np.argmin.
#define MTPB 128
__global__ __launch_bounds__(MTPB) void k_multi(
    const float* pred, const float* priors, const float* dec,
    const float* gtb, const int* gtl, const float* sumL1, const u8* validArr,
    const int* mlist, const int* mcnt,
    float* out, int N, int G, int C, int Nout)
{
  __shared__ float rv[MTPB];
  __shared__ int   rg[MTPB];
  int tid = threadIdx.x;
  int total = *mcnt;
  if (total > MAXMULTI) total = MAXMULTI;
  for (int w = blockIdx.x; w < total; w += gridDim.x) {
    int n = mlist[w];
    const float4 dvb = reinterpret_cast<const float4*>(dec)[n];
    const float4 pv  = reinterpret_cast<const float4*>(priors)[n];
    float s1 = sumL1[n];
    int vld = validArr[n];
    float best = 1e30f; int bg = INT_MAX;
    for (int gg = tid; gg < G; gg += MTPB) {
      float x0 = gtb[gg * 4 + 0], y0 = gtb[gg * 4 + 1];
      float x1 = gtb[gg * 4 + 2], y1 = gtb[gg * 4 + 3];
      float iou = f_iou(dvb.x, dvb.y, dvb.z, dvb.w, x0, y0, x1, y1);
      if (!vld) iou = 0.0f;
      int lb = gtl[gg];
      if (lb < 0) lb = 0;
      if (lb >= C) lb = C - 1;
      float dv = f_dv(pred[(size_t)n * C + lb]);
      float c = f_cost(iou, dv, s1, pv.x, pv.y, pv.z, pv.w, x0, y0, x1, y1, vld);
      if (c < best || (c == best && gg < bg)) { best = c; bg = gg; }
    }
    rv[tid] = best; rg[tid] = bg;
    __syncthreads();
    for (int st = MTPB / 2; st > 0; st >>= 1) {
      if (tid < st) {
        float v2 = rv[tid + st]; int g2 = rg[tid + st];
        float v1 = rv[tid];      int g1 = rg[tid];
        if (v2 < v1 || (v2 == v1 && g2 < g1)) { rv[tid] = v2; rg[tid] = g2; }
      }
      __syncthreads();
    }
    if (tid == 0) {
      int g = rg[0];
      if (g < 0 || g >= G) g = 0;
      float x0 = gtb[g * 4 + 0], y0 = gtb[g * 4 + 1];
      float x1 = gtb[g * 4 + 2], y1 = gtb[g * 4 + 3];
      float iou = f_iou(dvb.x, dvb.y, dvb.z, dvb.w, x0, y0, x1, y1);
      if (!vld) iou = 0.0f;
      out[n]            = (float)g;
      out[Nout + n]     = 1.0f;
      out[2 * Nout + n] = iou;
    }
    __syncthreads();  // protect rv/rg before next worklist item
  }
}

extern "C" void kernel_launch(void* const* d_in, const int* in_sizes, int n_in,
                              void* d_out, int out_size, void* d_ws, size_t ws_size,
                              hipStream_t stream) {
  const float* pred   = (const float*)d_in[0];  // (N,C) f32
  const float* priors = (const float*)d_in[1];  // (N,4) f32
  const float* dec    = (const float*)d_in[2];  // (N,4) f32
  const float* gtb    = (const float*)d_in[3];  // (G,4) f32
  const int*   gtl    = (const int*)d_in[4];    // (G,)  int32
  int N = in_sizes[2] / 4;
  int G = in_sizes[3] / 4;
  if (G > MAXG) G = MAXG;
  int C = in_sizes[0] / N;
  int Nout = out_size / 3;
  float* out = (float*)d_out;

  // ws layout (16B-aligned blocks). Zero-region [offZero, offValid+N) covers
  // gateCnt | flags | mcnt | pad | validArr in ONE memset.
  size_t offPacked = 0;
  size_t offSum    = offPacked + (size_t)N * 4;
  size_t offZero   = (offSum + (size_t)N * 4 + 15) & ~(size_t)15;
  size_t offFlags  = offZero + (size_t)G * 4;
  size_t offMcnt   = offFlags + (size_t)G * 4;
  size_t offValid  = (offMcnt + 4 + 15) & ~(size_t)15;
  size_t offMlist  = (offValid + (size_t)N + 15) & ~(size_t)15;
  size_t offGlist  = (offMlist + (size_t)MAXMULTI * 4 + 15) & ~(size_t)15;
  size_t offIouV   = offGlist + (size_t)G * GCAP * 4;
  size_t need      = offIouV + (size_t)G * ISPLIT * KTOP * 4;

  dim3 b(TPB);
  int nblk = (N + TPB - 1) / TPB;
  int oblk = (Nout + TPB - 1) / TPB;
  if (ws_size < need || d_ws == nullptr) {
    k_fallback<<<oblk, b, 0, stream>>>(out, Nout);  // sentinel: -70000 at out2
    return;
  }
  char* wsb = (char*)d_ws;
  u32* packed   = (u32*)(wsb + offPacked);
  float* sumL1  = (float*)(wsb + offSum);
  int* gateCnt  = (int*)(wsb + offZero);
  int* flags    = (int*)(wsb + offFlags);
  int* mcnt     = (int*)(wsb + offMcnt);
  u8* validArr  = (u8*)(wsb + offValid);
  int* mlist    = (int*)(wsb + offMlist);
  int* gateList = (int*)(wsb + offGlist);
  float* iouV   = (float*)(wsb + offIouV);

  // one memset: gateCnt+flags+mcnt+pad+validArr
  hipMemsetAsync(wsb + offZero, 0, offValid + (size_t)N - offZero, stream);

  int sumBlocks = ((N * 8) + TPB - 1) / TPB;
  int gateBlocks = G * GSPLIT;
  k_phase1<<<sumBlocks + gateBlocks, b, 0, stream>>>(
      pred, priors, gtb, sumL1, packed, validArr, gateCnt, gateList, flags,
      N, G, C, sumBlocks);
  k_iou_part<<<G * ISPLIT, dim3(ATPB), 0, stream>>>(dec, validArr, gtb, iouV, N, G);
  k_merge<<<G, dim3(ATPB), 0, stream>>>(iouV, gateCnt, gateList, flags,
                                        pred, priors, dec, sumL1, validArr, gtl, gtb,
                                        packed, G, N, C);
  k_final<<<nblk, b, 0, stream>>>(dec, gtb, validArr, packed, mlist, mcnt, out, N, G, Nout);
  k_multi<<<256, dim3(MTPB), 0, stream>>>(pred, priors, dec, gtb, gtl, sumL1, validArr,
                                          mlist, mcnt, out, N, G, C, Nout);
}